// Round 6
// baseline (301.517 us; speedup 1.0000x reference)
//
#include <hip/hip_runtime.h>
#include <math.h>

#define B_     1024
#define T_     80
#define D_     512
#define C_     78      // VOCAB+1
#define PRED_  30
#define BLANK_ 77
#define NKK    16      // 512 / 32
#define FRAG   512     // ushorts per fragment block (64 lanes * 8 halves)
#define PLANE_STRIDE (5 * NKK * FRAG)   // 40960 ushorts per plane
#define ROWS_PB 320    // rows per block (4 batch elements)
#define A_BYTES (ROWS_PB * 128)         // 40960 B per A slice (320 rows x 32 f32)

typedef __attribute__((ext_vector_type(8))) _Float16 f16x8;
typedef __attribute__((ext_vector_type(4))) float    f32x4;

#define WAITVM(N) asm volatile("s_waitcnt vmcnt(" #N ")" ::: "memory")

__device__ __forceinline__ void load_lds16(const void* g, void* l) {
    __builtin_amdgcn_global_load_lds(
        (const __attribute__((address_space(1))) unsigned int*)g,
        (__attribute__((address_space(3))) unsigned int*)l, 16, 0, 0);
}

// Split W [512,78] fp32 into two f16 planes (w1 = rnd(w), w2 = rnd(w - w1)),
// fragment-linear: [plane][ct][kk][lane][j] -> B load = base + lane*16B.
__global__ __launch_bounds__(256) void prep_w(const float* __restrict__ W,
                                              ushort* __restrict__ Wf) {
    int i = blockIdx.x * 256 + threadIdx.x;
    if (i >= 2 * PLANE_STRIDE) return;
    int j    = i & 7;
    int lane = (i >> 3) & 63;
    int kk   = (i >> 9) & 15;
    int rest = i >> 13;          // plane*5 + ct
    int ct   = rest % 5;
    int plane = rest / 5;
    int q = lane >> 4, n = lane & 15;
    int k = kk * 32 + q * 8 + j;
    int c = ct * 16 + n;
    float v = (c < C_) ? W[k * C_ + c] : 0.f;
    _Float16 h1 = (_Float16)v;
    union { _Float16 h; ushort u; } cv;
    cv.h = (plane == 0) ? h1 : (_Float16)(v - (float)h1);
    Wf[i] = cv.u;
}

// Block = 640 threads (10 waves) = 4 batch elements (320 rows), grid 256 =
// one block/CU. Wave w: rows [w*32, w*32+32) as two 16-row MFMA tiles.
// A: staged to LDS (3-buffer ring, 2 slices ahead, XOR-swizzled chunks).
// B: per-wave DIRECT global->reg loads (L2-resident 160 KB hot set), double-
// buffered 1 slice ahead. The vmem queue per wave is the strict sequence
// [A(k+2):4][B(k+1):10] (pinned by sched_barrier), so a counted
// `s_waitcnt vmcnt(24)` (= loads issued after A(k)) retires exactly A(k)
// while A(k+1),A(k+2),B(k),B(k+1) stay in flight ACROSS the s_barrier.
__global__ __launch_bounds__(640) void gemm_ctc(
    const float* __restrict__ feat,   // [81920, 512] fp32
    const ushort* __restrict__ Wf,    // f16 split planes, fragment-linear
    const float* __restrict__ bias,   // [78] fp32
    float* __restrict__ probs,        // [81920, 78] fp32
    float* __restrict__ lab)          // [1024, 30] fp32
{
    __shared__ __align__(16) unsigned char Sbuf[3][A_BYTES];  // 3 x 40 KB
    __shared__ int best_s[4][T_];

    const int tid  = threadIdx.x;
    const int w    = tid >> 6;      // 0..9
    const int lane = tid & 63;
    const int q    = lane >> 4;
    const int n    = lane & 15;

    const float*  Abase = feat + (size_t)blockIdx.x * ROWS_PB * D_;
    const ushort* bpL   = Wf + lane * 8;

    // stage A slice kk (320 rows x 32 f32) into ring buffer buf, XOR-swizzled
    // 16B chunks: LDS chunk pos (row,pc) holds global chunk pc ^ (row&7).
    auto stage_a = [&](int buf, int kk) {
        #pragma unroll
        for (int l = 0; l < 4; ++l) {
            int rb  = w * 4 + l;             // 0..39 (8-row groups)
            int row = rb * 8 + (lane >> 3);
            int pc  = lane & 7;
            int sc  = pc ^ (row & 7);
            const float* g = Abase + (size_t)row * D_ + kk * 32 + sc * 4;
            load_lds16(g, Sbuf[buf] + rb * 1024);   // dst wave-uniform
        }
    };

    f16x8 bs[2][10];                 // B double buffer: [set][plane*5+ct]
    auto loadB = [&](int si, int kk) {
        #pragma unroll
        for (int f = 0; f < 10; ++f) {
            int plane = f / 5, ct = f % 5;   // constants after unroll
            bs[si][f] = *(const f16x8*)(bpL + (size_t)plane * PLANE_STRIDE
                                            + (ct * NKK + kk) * FRAG);
        }
    };

    f32x4 acc[2][5];
    #pragma unroll
    for (int t = 0; t < 2; ++t)
        #pragma unroll
        for (int ct = 0; ct < 5; ++ct)
            acc[t][ct] = (f32x4){0.f, 0.f, 0.f, 0.f};

    auto body = [&](int buf, int si) {
        const float* Ab = (const float*)(Sbuf[buf]);
        f16x8 a1f[2], a2f[2];
        #pragma unroll
        for (int t = 0; t < 2; ++t) {
            int rowl = w * 32 + t * 16 + n;
            int sw   = n & 7;                // rowl&7 == n&7 (base mult of 16)
            float4 f0 = *(const float4*)(Ab + rowl * 32 + (((2 * q)     ^ sw) * 4));
            float4 f1 = *(const float4*)(Ab + rowl * 32 + (((2 * q + 1) ^ sw) * 4));
            float v[8] = {f0.x, f0.y, f0.z, f0.w, f1.x, f1.y, f1.z, f1.w};
            #pragma unroll
            for (int j = 0; j < 8; ++j) {
                _Float16 h = (_Float16)v[j];
                a1f[t][j] = h;
                a2f[t][j] = (_Float16)(v[j] - (float)h);
            }
        }
        #pragma unroll
        for (int ct = 0; ct < 5; ++ct) {
            f16x8 b1 = bs[si][ct];
            f16x8 b2 = bs[si][5 + ct];
            acc[0][ct] = __builtin_amdgcn_mfma_f32_16x16x32_f16(a1f[0], b1, acc[0][ct], 0, 0, 0);
            acc[0][ct] = __builtin_amdgcn_mfma_f32_16x16x32_f16(a2f[0], b1, acc[0][ct], 0, 0, 0);
            acc[0][ct] = __builtin_amdgcn_mfma_f32_16x16x32_f16(a1f[0], b2, acc[0][ct], 0, 0, 0);
            acc[1][ct] = __builtin_amdgcn_mfma_f32_16x16x32_f16(a1f[1], b1, acc[1][ct], 0, 0, 0);
            acc[1][ct] = __builtin_amdgcn_mfma_f32_16x16x32_f16(a2f[1], b1, acc[1][ct], 0, 0, 0);
            acc[1][ct] = __builtin_amdgcn_mfma_f32_16x16x32_f16(a1f[1], b2, acc[1][ct], 0, 0, 0);
        }
    };

    // prologue: queue = [A(0):4][B(0):10][A(1):4]
    stage_a(0, 0);
    __builtin_amdgcn_sched_barrier(0);
    loadB(0, 0);
    __builtin_amdgcn_sched_barrier(0);
    stage_a(1, 1);
    __builtin_amdgcn_sched_barrier(0);

    // Per iter K: wait(N) = #loads issued after A(K) -> A(K) retired, rest in
    // flight. N: K=0:14 (B0+A1), K=1:14 (A2+B1), K=2..14:24 (B(K-1)+A(K+1)+
    // B(K)), K=15: drain.
    #define ITER(K, NW)                                                   \
        WAITVM(NW);                                                       \
        __builtin_amdgcn_s_barrier();                                     \
        __builtin_amdgcn_sched_barrier(0);                                \
        if ((K) <= 13) stage_a(((K) + 2) % 3, (K) + 2);                   \
        __builtin_amdgcn_sched_barrier(0);                                \
        if ((K) <= 14) loadB(((K) + 1) & 1, (K) + 1);                     \
        __builtin_amdgcn_sched_barrier(0);                                \
        body((K) % 3, (K) & 1);

    ITER(0, 14)  ITER(1, 14)  ITER(2, 24)  ITER(3, 24)
    ITER(4, 24)  ITER(5, 24)  ITER(6, 24)  ITER(7, 24)
    ITER(8, 24)  ITER(9, 24)  ITER(10, 24) ITER(11, 24)
    ITER(12, 24) ITER(13, 24) ITER(14, 24) ITER(15, 0)
    #undef ITER

    // ---- epilogue: bias + argmax + softmax + nontemporal stores ----
    #pragma unroll
    for (int t = 0; t < 2; ++t) {
        float x[5][4];
        #pragma unroll
        for (int ct = 0; ct < 5; ++ct) {
            int c = ct * 16 + n;
            bool valid = (c < C_);
            float bv = valid ? bias[c] : 0.f;
            #pragma unroll
            for (int r = 0; r < 4; ++r)
                x[ct][r] = valid ? (acc[t][ct][r] + bv) : -INFINITY;
        }
        float av[4]; int ai[4];
        #pragma unroll
        for (int r = 0; r < 4; ++r) {
            av[r] = x[0][r]; ai[r] = n;
            #pragma unroll
            for (int ct = 1; ct < 5; ++ct) {
                int c = ct * 16 + n;
                if (x[ct][r] > av[r]) { av[r] = x[ct][r]; ai[r] = c; }
            }
        }
        #pragma unroll
        for (int off = 8; off >= 1; off >>= 1) {
            #pragma unroll
            for (int r = 0; r < 4; ++r) {
                float ov = __shfl_xor(av[r], off, 16);
                int   oi = __shfl_xor(ai[r], off, 16);
                if (ov > av[r] || (ov == av[r] && oi < ai[r])) { av[r] = ov; ai[r] = oi; }
            }
        }
        float s[4] = {0.f, 0.f, 0.f, 0.f};
        #pragma unroll
        for (int ct = 0; ct < 5; ++ct)
            #pragma unroll
            for (int r = 0; r < 4; ++r) {
                x[ct][r] = __expf(x[ct][r] - av[r]);   // -INF -> 0
                s[r] += x[ct][r];
            }
        #pragma unroll
        for (int off = 8; off >= 1; off >>= 1)
            #pragma unroll
            for (int r = 0; r < 4; ++r) s[r] += __shfl_xor(s[r], off, 16);

        const size_t growb = (size_t)blockIdx.x * ROWS_PB + w * 32 + t * 16 + q * 4;
        #pragma unroll
        for (int r = 0; r < 4; ++r) {
            float inv = 1.f / s[r];
            float* op = probs + (growb + r) * C_;
            #pragma unroll
            for (int ct = 0; ct < 5; ++ct) {
                int c = ct * 16 + n;
                if (c < C_) __builtin_nontemporal_store(x[ct][r] * inv, op + c);
            }
        }
        if (n == 0) {
            int rl = w * 32 + t * 16 + q * 4;   // 0..319
            #pragma unroll
            for (int r = 0; r < 4; ++r) {
                int rr = rl + r;
                best_s[rr / T_][rr % T_] = ai[r];
            }
        }
    }
    __syncthreads();

    // in-block CTC greedy decode (4 batch elements)
    if (tid < 4) {
        const int* bs2 = best_s[tid];
        float* op = lab + ((size_t)blockIdx.x * 4 + tid) * PRED_;
        int prev = -1, pos = 0;
        for (int t2 = 0; t2 < T_; ++t2) {
            int v = bs2[t2];
            if (v != BLANK_ && v != prev) {
                if (pos < PRED_) op[pos] = (float)v;
                ++pos;
            }
            prev = v;
        }
        for (int i2 = (pos < PRED_ ? pos : PRED_); i2 < PRED_; ++i2) op[i2] = -1.f;
    }
}

extern "C" void kernel_launch(void* const* d_in, const int* in_sizes, int n_in,
                              void* d_out, int out_size, void* d_ws, size_t ws_size,
                              hipStream_t stream) {
    const float* feat = (const float*)d_in[0];   // fp32 [1024,80,512]
    const float* W    = (const float*)d_in[1];   // fp32 [512,78]
    const float* bias = (const float*)d_in[2];   // fp32 [78]
    // d_in[3]=y, d_in[4]=times : unused
    float*  probs = (float*)d_out;
    float*  lab   = probs + (size_t)B_ * T_ * C_;
    ushort* Wf    = (ushort*)d_ws;               // 163840 B scratch

    hipLaunchKernelGGL(prep_w, dim3(320), dim3(256), 0, stream, W, Wf);
    hipLaunchKernelGGL(gemm_ctc, dim3(B_ / 4), dim3(640), 0, stream,
                       feat, Wf, bias, probs, lab);
}

// Round 7
// 270.257 us; speedup vs baseline: 1.1157x; 1.1157x over previous
//
#include <hip/hip_runtime.h>
#include <math.h>

#define B_     1024
#define T_     80
#define D_     512
#define C_     78      // VOCAB+1
#define PRED_  30
#define BLANK_ 77
#define NKK    16      // 512 / 32
#define FRAG   512     // ushorts per fragment block (64 lanes * 8 halves)
#define PLANE_STRIDE (5 * NKK * FRAG)   // 40960 ushorts per plane
#define ROWS_PB 64     // rows per block
#define QBYTES  (ROWS_PB * 512)         // 32 KB: quarter-K slice (64 rows x 128 f32)

typedef __attribute__((ext_vector_type(8))) _Float16 f16x8;
typedef __attribute__((ext_vector_type(4))) float    f32x4;

#define WAITVM(N) asm volatile("s_waitcnt vmcnt(" #N ")" ::: "memory")
#define SB __builtin_amdgcn_sched_barrier(0)

__device__ __forceinline__ void load_lds16(const void* g, void* l) {
    __builtin_amdgcn_global_load_lds(
        (const __attribute__((address_space(1))) unsigned int*)g,
        (__attribute__((address_space(3))) unsigned int*)l, 16, 0, 0);
}

// Split W [512,78] fp32 into two f16 planes (w1 = rnd(w), w2 = rnd(w - w1)),
// fragment-linear: [plane][ct][kk][lane][j] -> B load = base + lane*16B.
__global__ __launch_bounds__(256) void prep_w(const float* __restrict__ W,
                                              ushort* __restrict__ Wf) {
    int i = blockIdx.x * 256 + threadIdx.x;
    if (i >= 2 * PLANE_STRIDE) return;
    int j    = i & 7;
    int lane = (i >> 3) & 63;
    int kk   = (i >> 9) & 15;
    int rest = i >> 13;          // plane*5 + ct
    int ct   = rest % 5;
    int plane = rest / 5;
    int q = lane >> 4, n = lane & 15;
    int k = kk * 32 + q * 8 + j;
    int c = ct * 16 + n;
    float v = (c < C_) ? W[k * C_ + c] : 0.f;
    _Float16 h1 = (_Float16)v;
    union { _Float16 h; ushort u; } cv;
    cv.h = (plane == 0) ? h1 : (_Float16)(v - (float)h1);
    Wf[i] = cv.u;
}

// Block = 256 threads (4 waves) = 64 rows; wave w owns the 16-row tile
// [w*16, w*16+16), all 78 (pad 80) cols. Grid 1280 -> 2 blocks/CU (64 KB LDS).
//
// KEY CHANGE vs prior rounds: A is staged in QUARTER-K slices — each stage
// reads 512 CONTIGUOUS bytes per feat row (4 full cache lines), not 128 B.
// This kills the stride-2048 column-walk (16x DRAM page re-activation) that
// capped every previous variant at ~2.6 TB/s aggregate.
//   LDS: Abuf[2][64 rows][128 f32], chunk-XOR-swizzled via the SOURCE address
//   (LDS (row,pc) holds global chunk pc^(row&7) of that row's quarter).
// B: per-wave register double-buffer, two NAMED sets (bE/bO), all indices
// compile-time (spill-proof), 1 kk ahead, loads from L2-hot Wf.
// Counted WAITVM(28/20) at the 4 barrier points only — lookahead never drains.
__global__ __launch_bounds__(256) void gemm_ctc(
    const float* __restrict__ feat,   // [81920, 512] fp32
    const ushort* __restrict__ Wf,    // f16 split planes, fragment-linear
    const float* __restrict__ bias,   // [78] fp32
    float* __restrict__ probs)        // [81920, 78] fp32
{
    __shared__ __align__(16) unsigned char Abuf[2][QBYTES];  // 2 x 32 KB

    const int tid  = threadIdx.x;
    const int w    = tid >> 6;      // 0..3
    const int lane = tid & 63;
    const int q    = lane >> 4;
    const int n    = lane & 15;

    const float*  Abase = feat + (size_t)blockIdx.x * ROWS_PB * D_;
    const ushort* bpL   = Wf + lane * 8;

    // stage quarter q4 (k in [q4*128, q4*128+128)) into Abuf[q4&1].
    // 2048 chunks of 16 B; thread covers chunk c = l*256+tid; contiguous
    // 512-B runs per row in global (XOR only permutes within 128-B lines).
    auto stageA = [&](int q4) {
        #pragma unroll
        for (int l = 0; l < 8; ++l) {
            int c   = l * 256 + tid;
            int row = c >> 5;            // 0..63
            int pos = c & 31;
            int kl  = pos >> 3;          // local kk 0..3
            int pc  = pos & 7;
            const float* g = Abase + (size_t)row * D_ + q4 * 128 + kl * 32
                                   + (pc ^ (row & 7)) * 4;
            load_lds16(g, Abuf[q4 & 1] + (size_t)(l * 256 + w * 64) * 16);
        }
    };

    f16x8 bE[10], bO[10];            // [plane*5+ct], named sets (even/odd kk)
    #define ISSB(SET, KK) { _Pragma("unroll")                                  \
        for (int f = 0; f < 10; ++f) {                                         \
            int pl = f / 5, ct = f % 5;                                        \
            SET[f] = *(const f16x8*)(bpL + (size_t)pl * PLANE_STRIDE           \
                                         + (ct * NKK + (KK)) * FRAG); } }

    f32x4 acc[5];
    #pragma unroll
    for (int ct = 0; ct < 5; ++ct)
        acc[ct] = (f32x4){0.f, 0.f, 0.f, 0.f};

    #define BODY(SET, KK) {                                                    \
        const float* Ab = (const float*)(Abuf[((KK) >> 2) & 1]);               \
        int rowl = w * 16 + n;                                                 \
        int sw   = n & 7;                                                      \
        float4 f0 = *(const float4*)(Ab + rowl * 128 + ((KK) & 3) * 32         \
                                        + (((2 * q)     ^ sw) * 4));           \
        float4 f1 = *(const float4*)(Ab + rowl * 128 + ((KK) & 3) * 32         \
                                        + (((2 * q + 1) ^ sw) * 4));           \
        float v[8] = {f0.x, f0.y, f0.z, f0.w, f1.x, f1.y, f1.z, f1.w};         \
        f16x8 a1f, a2f;                                                        \
        _Pragma("unroll")                                                      \
        for (int j = 0; j < 8; ++j) {                                          \
            _Float16 h = (_Float16)v[j];                                       \
            a1f[j] = h;                                                        \
            a2f[j] = (_Float16)(v[j] - (float)h);                              \
        }                                                                      \
        _Pragma("unroll")                                                      \
        for (int ct = 0; ct < 5; ++ct) {                                       \
            acc[ct] = __builtin_amdgcn_mfma_f32_16x16x32_f16(a1f, SET[ct],     \
                                                             acc[ct], 0,0,0);  \
            acc[ct] = __builtin_amdgcn_mfma_f32_16x16x32_f16(a2f, SET[ct],     \
                                                             acc[ct], 0,0,0);  \
            acc[ct] = __builtin_amdgcn_mfma_f32_16x16x32_f16(a1f, SET[5+ct],   \
                                                             acc[ct], 0,0,0);  \
        } }

    // ---- pipeline (issue-order pinned by SB; ledger in comments) ----
    // prologue: [A0:8][B0:10][B1:10][A1:8] = 36 out; wait 28 -> A0 retired.
    stageA(0); SB; ISSB(bE, 0); SB; ISSB(bO, 1); SB; stageA(1); SB;
    WAITVM(28);
    __builtin_amdgcn_s_barrier(); SB;
    // q0: bodies 0-3 read buf0; B(kk) auto-waited by compiler via reg deps.
    BODY(bE, 0);  SB; ISSB(bE, 2);  SB;
    BODY(bO, 1);  SB; ISSB(bO, 3);  SB;
    BODY(bE, 2);  SB; ISSB(bE, 4);  SB;
    BODY(bO, 3);  SB; ISSB(bO, 5);  SB;
    WAITVM(20);                       // out: B4,B5 -> A1 retired for all
    __builtin_amdgcn_s_barrier(); SB; // buf0 free: nobody reads it in q1
    stageA(2); SB;                    // A2 -> buf0, lands during q1
    BODY(bE, 4);  SB; ISSB(bE, 6);  SB;
    BODY(bO, 5);  SB; ISSB(bO, 7);  SB;
    BODY(bE, 6);  SB; ISSB(bE, 8);  SB;
    BODY(bO, 7);  SB; ISSB(bO, 9);  SB;
    WAITVM(20);                       // out: B8,B9 -> A2 retired
    __builtin_amdgcn_s_barrier(); SB;
    stageA(3); SB;                    // A3 -> buf1, lands during q2
    BODY(bE, 8);  SB; ISSB(bE, 10); SB;
    BODY(bO, 9);  SB; ISSB(bO, 11); SB;
    BODY(bE, 10); SB; ISSB(bE, 12); SB;
    BODY(bO, 11); SB; ISSB(bO, 13); SB;
    WAITVM(20);                       // out: B12,B13 -> A3 retired
    __builtin_amdgcn_s_barrier(); SB;
    BODY(bE, 12); SB; ISSB(bE, 14); SB;
    BODY(bO, 13); SB; ISSB(bO, 15); SB;
    BODY(bE, 14); SB;
    BODY(bO, 15);
    #undef BODY
    #undef ISSB

    // ---- epilogue: bias + softmax + nontemporal stores ----
    float x[5][4];
    #pragma unroll
    for (int ct = 0; ct < 5; ++ct) {
        int c = ct * 16 + n;
        bool valid = (c < C_);
        float bv = valid ? bias[c] : 0.f;
        #pragma unroll
        for (int r = 0; r < 4; ++r)
            x[ct][r] = valid ? (acc[ct][r] + bv) : -INFINITY;
    }
    float av[4];
    #pragma unroll
    for (int r = 0; r < 4; ++r) {
        av[r] = x[0][r];
        #pragma unroll
        for (int ct = 1; ct < 5; ++ct) av[r] = fmaxf(av[r], x[ct][r]);
    }
    #pragma unroll
    for (int off = 8; off >= 1; off >>= 1)
        #pragma unroll
        for (int r = 0; r < 4; ++r) av[r] = fmaxf(av[r], __shfl_xor(av[r], off, 16));
    float s[4] = {0.f, 0.f, 0.f, 0.f};
    #pragma unroll
    for (int ct = 0; ct < 5; ++ct)
        #pragma unroll
        for (int r = 0; r < 4; ++r) {
            x[ct][r] = __expf(x[ct][r] - av[r]);   // -INF -> 0
            s[r] += x[ct][r];
        }
    #pragma unroll
    for (int off = 8; off >= 1; off >>= 1)
        #pragma unroll
        for (int r = 0; r < 4; ++r) s[r] += __shfl_xor(s[r], off, 16);

    // wave w covers global rows blk*64 + w*16 + q*4 + r
    const size_t growb = (size_t)blockIdx.x * ROWS_PB + w * 16 + q * 4;
    #pragma unroll
    for (int r = 0; r < 4; ++r) {
        float inv = 1.f / s[r];
        float* op = probs + (growb + r) * C_;
        #pragma unroll
        for (int ct = 0; ct < 5; ++ct) {
            int c = ct * 16 + n;
            if (c < C_) __builtin_nontemporal_store(x[ct][r] * inv, op + c);
        }
    }
}

// CTC greedy decode from probs (softmax is monotone: argmax(probs) ==
// argmax(logits); reference itself argmaxes the softmax output).
// Block = 128 threads = one batch element; lanes 0..79 own one time-step.
__global__ __launch_bounds__(128) void decode_ctc(
    const float* __restrict__ probs,  // [81920, 78]
    float* __restrict__ lab)          // [1024, 30]
{
    __shared__ int am[T_];
    const int b = blockIdx.x;
    const int t = threadIdx.x;
    if (t < T_) {
        const float* row = probs + ((size_t)b * T_ + t) * C_;
        float m = row[0]; int idx = 0;
        for (int c = 1; c < C_; ++c) {
            float v = row[c];
            if (v > m) { m = v; idx = c; }     // strict > : first max wins
        }
        am[t] = idx;
    }
    __syncthreads();
    if (t == 0) {
        float* op = lab + (size_t)b * PRED_;
        int prev = -1, pos = 0;
        for (int t2 = 0; t2 < T_; ++t2) {
            int v = am[t2];
            if (v != BLANK_ && v != prev) {
                if (pos < PRED_) op[pos] = (float)v;
                ++pos;
            }
            prev = v;
        }
        for (int i2 = (pos < PRED_ ? pos : PRED_); i2 < PRED_; ++i2) op[i2] = -1.f;
    }
}

extern "C" void kernel_launch(void* const* d_in, const int* in_sizes, int n_in,
                              void* d_out, int out_size, void* d_ws, size_t ws_size,
                              hipStream_t stream) {
    const float* feat = (const float*)d_in[0];   // fp32 [1024,80,512]
    const float* W    = (const float*)d_in[1];   // fp32 [512,78]
    const float* bias = (const float*)d_in[2];   // fp32 [78]
    // d_in[3]=y, d_in[4]=times : unused
    float*  probs = (float*)d_out;
    float*  lab   = probs + (size_t)B_ * T_ * C_;
    ushort* Wf    = (ushort*)d_ws;               // 163840 B scratch

    hipLaunchKernelGGL(prep_w, dim3(320), dim3(256), 0, stream, W, Wf);
    hipLaunchKernelGGL(gemm_ctc, dim3(B_ * T_ / ROWS_PB), dim3(256), 0, stream,
                       feat, Wf, bias, probs);
    hipLaunchKernelGGL(decode_ctc, dim3(B_), dim3(128), 0, stream, probs, lab);
}

// Round 8
// 262.787 us; speedup vs baseline: 1.1474x; 1.0284x over previous
//
#include <hip/hip_runtime.h>
#include <math.h>

#define B_     1024
#define T_     80
#define D_     512
#define C_     78      // VOCAB+1
#define PRED_  30
#define BLANK_ 77
#define NKK    16      // 512 / 32
#define FRAG   512     // ushorts per fragment block (64 lanes * 8 halves)
#define PLANE_STRIDE (5 * NKK * FRAG)   // 40960 ushorts per plane
#define ROWS_PB 160    // rows per block (2 batch elements)
#define A_SL   40960   // bytes per A eighth-slice: 160 rows x 64 f32 (256 B/row)
#define B_SL   20480   // bytes per B eighth-slice: 20 slots (2 planes x 5ct x 2kk) x 1 KB

typedef __attribute__((ext_vector_type(8))) _Float16 f16x8;
typedef __attribute__((ext_vector_type(4))) float    f32x4;

#define WAITVM(N) asm volatile("s_waitcnt vmcnt(" #N ")" ::: "memory")
#define SB __builtin_amdgcn_sched_barrier(0)

__device__ __forceinline__ void load_lds16(const void* g, void* l) {
    __builtin_amdgcn_global_load_lds(
        (const __attribute__((address_space(1))) unsigned int*)g,
        (__attribute__((address_space(3))) unsigned int*)l, 16, 0, 0);
}

// Split W [512,78] fp32 into two f16 planes (w1 = rnd(w), w2 = rnd(w - w1)),
// fragment-linear: [plane][ct][kk][lane][j] -> stage load = base + lane*16B.
__global__ __launch_bounds__(256) void prep_w(const float* __restrict__ W,
                                              ushort* __restrict__ Wf) {
    int i = blockIdx.x * 256 + threadIdx.x;
    if (i >= 2 * PLANE_STRIDE) return;
    int j    = i & 7;
    int lane = (i >> 3) & 63;
    int kk   = (i >> 9) & 15;
    int rest = i >> 13;          // plane*5 + ct
    int ct   = rest % 5;
    int plane = rest / 5;
    int q = lane >> 4, n = lane & 15;
    int k = kk * 32 + q * 8 + j;
    int c = ct * 16 + n;
    float v = (c < C_) ? W[k * C_ + c] : 0.f;
    _Float16 h1 = (_Float16)v;
    union { _Float16 h; ushort u; } cv;
    cv.h = (plane == 0) ? h1 : (_Float16)(v - (float)h1);
    Wf[i] = cv.u;
}

// Block = 640 threads (10 waves) = 2 batch elements (160 rows); wave w owns
// the 16-row tile [w*16, w*16+16), all 78 (pad 80) cols. Grid 512 -> 2
// sequential blocks/CU (1 resident, 123.5 KB LDS).
//
// Consolidates the surviving levers of R0-R7:
//  - A staged in EIGHTH-K slices: 256 CONTIGUOUS bytes per feat row per stage
//    (vs 128 B in R0-R5), XOR-swizzled 16B chunks via source address.
//  - B staged to LDS per slice (20 x 1KB slots, 2 slots/wave) and shared by
//    all 10 waves via ds_read -> per-CU B traffic 4x lower than per-wave
//    register loads (R7).
//  - Counted vmcnt(6) double-buffer pipeline: bundle(e) = [A:4][B:2] loads
//    per thread; at phase e, WAITVM(6) retires exactly bundle(e) while
//    bundle(e+1) stays in flight ACROSS the raw s_barrier. bundle(e+2) is
//    issued only after the phase-e read barrier (its LDS target is the buffer
//    phase e just finished reading; ds_read completion is guaranteed by the
//    MFMA data deps that precede the barrier in program order).
//  - In-block CTC decode (2 batch elements) - no third kernel, no probs
//    re-read.
__global__ __launch_bounds__(640) void gemm_ctc(
    const float* __restrict__ feat,   // [81920, 512] fp32
    const ushort* __restrict__ Wf,    // f16 split planes, fragment-linear
    const float* __restrict__ bias,   // [78] fp32
    float* __restrict__ probs,        // [81920, 78] fp32
    float* __restrict__ lab)          // [1024, 30] fp32
{
    __shared__ __align__(16) unsigned char Abuf[2][A_SL];  // 2 x 40 KB
    __shared__ __align__(16) unsigned char Bbuf[2][B_SL];  // 2 x 20 KB
    __shared__ int best_s[2][T_];

    const int tid  = threadIdx.x;
    const int w    = tid >> 6;      // 0..9
    const int lane = tid & 63;
    const int q    = lane >> 4;
    const int n    = lane & 15;

    const float* Abase = feat + (size_t)blockIdx.x * ROWS_PB * D_;

    // bundle(e): stage A eighth e (k in [e*64, e*64+64)) + B eighth e.
    // A: 2560 16-B chunks, 4/thread; row-major [row][kl][pc], pc holds global
    //    chunk pc^(row&7) (XOR on the SOURCE address, LDS stays linear).
    //    Each row is a 256-B contiguous global run (2 cache lines).
    // B: 20 slots of 1 KB; slot s = plane*10 + ct*2 + kl (kk = 2e+kl);
    //    wave w stages slots {2w, 2w+1} (wave-uniform dest + lane*16).
    auto bundle = [&](int e) {
        unsigned char* Ad = Abuf[e & 1];
        unsigned char* Bd = Bbuf[e & 1];
        #pragma unroll
        for (int l = 0; l < 4; ++l) {
            int c   = l * 640 + tid;
            int row = c >> 4;            // 0..159
            int pos = c & 15;
            int kl  = pos >> 3;          // which 32-k half of the eighth
            int pc  = pos & 7;
            const float* g = Abase + (size_t)row * D_ + e * 64 + kl * 32
                                   + (pc ^ (row & 7)) * 4;
            load_lds16(g, Ad + (size_t)(l * 640 + w * 64) * 16);
        }
        #pragma unroll
        for (int i = 0; i < 2; ++i) {
            int s  = w * 2 + i;          // 0..19
            int p  = (s >= 10) ? 1 : 0;
            int s2 = s - p * 10;
            int ct = s2 >> 1;
            int kl = s2 & 1;
            const ushort* g = Wf + (size_t)p * PLANE_STRIDE
                                 + (ct * NKK + 2 * e + kl) * FRAG + lane * 8;
            load_lds16(g, Bd + (size_t)s * 1024);
        }
    };

    f32x4 acc[5];
    #pragma unroll
    for (int ct = 0; ct < 5; ++ct)
        acc[ct] = (f32x4){0.f, 0.f, 0.f, 0.f};

    #define BODY(KK) {                                                         \
        const float*  Ab = (const float*)(Abuf[((KK) >> 1) & 1]);              \
        const ushort* Bb = (const ushort*)(Bbuf[((KK) >> 1) & 1]);             \
        const int kl  = (KK) & 1;                                              \
        int rowl = w * 16 + n;                                                 \
        int sw   = n & 7;             /* rowl&7 == n&7 (w*16 mult of 8) */     \
        float4 f0 = *(const float4*)(Ab + rowl * 64 + kl * 32                  \
                                        + (((2 * q)     ^ sw) * 4));           \
        float4 f1 = *(const float4*)(Ab + rowl * 64 + kl * 32                  \
                                        + (((2 * q + 1) ^ sw) * 4));           \
        float v[8] = {f0.x, f0.y, f0.z, f0.w, f1.x, f1.y, f1.z, f1.w};         \
        f16x8 a1f, a2f;                                                        \
        _Pragma("unroll")                                                      \
        for (int j = 0; j < 8; ++j) {                                          \
            _Float16 h = (_Float16)v[j];                                       \
            a1f[j] = h;                                                        \
            a2f[j] = (_Float16)(v[j] - (float)h);                              \
        }                                                                      \
        _Pragma("unroll")                                                      \
        for (int ct = 0; ct < 5; ++ct) {                                       \
            f16x8 b1 = *(const f16x8*)(Bb + (ct * 2 + kl) * 512 + lane * 8);   \
            f16x8 b2 = *(const f16x8*)(Bb + (10 + ct * 2 + kl) * 512 + lane * 8);\
            acc[ct] = __builtin_amdgcn_mfma_f32_16x16x32_f16(a1f, b1,          \
                                                             acc[ct], 0,0,0);  \
            acc[ct] = __builtin_amdgcn_mfma_f32_16x16x32_f16(a2f, b1,          \
                                                             acc[ct], 0,0,0);  \
            acc[ct] = __builtin_amdgcn_mfma_f32_16x16x32_f16(a1f, b2,          \
                                                             acc[ct], 0,0,0);  \
        } }

    // prologue: bundles 0,1 in flight (12 loads/thread)
    bundle(0); SB;
    bundle(1); SB;

    // Phase e: WAITVM(6) -> bundle(e) retired, bundle(e+1) in flight across
    // the barrier. After the read-complete barrier, issue bundle(e+2) into
    // the buffer phase e just finished with.
    #define PH(E, NW)                                                          \
        WAITVM(NW);                                                            \
        __builtin_amdgcn_s_barrier(); SB;                                      \
        BODY(2 * (E));                                                         \
        BODY(2 * (E) + 1);                                                     \
        SB;                                                                    \
        __builtin_amdgcn_s_barrier(); SB;                                      \
        if ((E) <= 5) { bundle((E) + 2); SB; }

    PH(0, 6) PH(1, 6) PH(2, 6) PH(3, 6)
    PH(4, 6) PH(5, 6) PH(6, 6) PH(7, 0)
    #undef PH
    #undef BODY

    // ---- epilogue: bias + argmax + softmax + nontemporal stores ----
    float x[5][4];
    #pragma unroll
    for (int ct = 0; ct < 5; ++ct) {
        int c = ct * 16 + n;
        bool valid = (c < C_);
        float bv = valid ? bias[c] : 0.f;
        #pragma unroll
        for (int r = 0; r < 4; ++r)
            x[ct][r] = valid ? (acc[ct][r] + bv) : -INFINITY;
    }
    float av[4]; int ai[4];
    #pragma unroll
    for (int r = 0; r < 4; ++r) {
        av[r] = x[0][r]; ai[r] = n;
        #pragma unroll
        for (int ct = 1; ct < 5; ++ct) {
            int c = ct * 16 + n;
            if (x[ct][r] > av[r]) { av[r] = x[ct][r]; ai[r] = c; }
        }
    }
    #pragma unroll
    for (int off = 8; off >= 1; off >>= 1) {
        #pragma unroll
        for (int r = 0; r < 4; ++r) {
            float ov = __shfl_xor(av[r], off, 16);
            int   oi = __shfl_xor(ai[r], off, 16);
            if (ov > av[r] || (ov == av[r] && oi < ai[r])) { av[r] = ov; ai[r] = oi; }
        }
    }
    float s[4] = {0.f, 0.f, 0.f, 0.f};
    #pragma unroll
    for (int ct = 0; ct < 5; ++ct)
        #pragma unroll
        for (int r = 0; r < 4; ++r) {
            x[ct][r] = __expf(x[ct][r] - av[r]);   // -INF -> 0
            s[r] += x[ct][r];
        }
    #pragma unroll
    for (int off = 8; off >= 1; off >>= 1)
        #pragma unroll
        for (int r = 0; r < 4; ++r) s[r] += __shfl_xor(s[r], off, 16);

    // wave w covers global rows blk*160 + w*16 + q*4 + r
    const size_t growb = (size_t)blockIdx.x * ROWS_PB + w * 16 + q * 4;
    #pragma unroll
    for (int r = 0; r < 4; ++r) {
        float inv = 1.f / s[r];
        float* op = probs + (growb + r) * C_;
        #pragma unroll
        for (int ct = 0; ct < 5; ++ct) {
            int c = ct * 16 + n;
            if (c < C_) __builtin_nontemporal_store(x[ct][r] * inv, op + c);
        }
    }
    if (n == 0) {
        int rl = w * 16 + q * 4;             // 0..159
        #pragma unroll
        for (int r = 0; r < 4; ++r) {
            int rr = rl + r;
            best_s[rr / T_][rr % T_] = ai[r];
        }
    }
    __syncthreads();

    // in-block CTC greedy decode (2 batch elements)
    if (tid < 2) {
        const int* bs = best_s[tid];
        float* op = lab + ((size_t)blockIdx.x * 2 + tid) * PRED_;
        int prev = -1, pos = 0;
        for (int t2 = 0; t2 < T_; ++t2) {
            int v = bs[t2];
            if (v != BLANK_ && v != prev) {
                if (pos < PRED_) op[pos] = (float)v;
                ++pos;
            }
            prev = v;
        }
        for (int i2 = (pos < PRED_ ? pos : PRED_); i2 < PRED_; ++i2) op[i2] = -1.f;
    }
}

extern "C" void kernel_launch(void* const* d_in, const int* in_sizes, int n_in,
                              void* d_out, int out_size, void* d_ws, size_t ws_size,
                              hipStream_t stream) {
    const float* feat = (const float*)d_in[0];   // fp32 [1024,80,512]
    const float* W    = (const float*)d_in[1];   // fp32 [512,78]
    const float* bias = (const float*)d_in[2];   // fp32 [78]
    // d_in[3]=y, d_in[4]=times : unused
    float*  probs = (float*)d_out;
    float*  lab   = probs + (size_t)B_ * T_ * C_;
    ushort* Wf    = (ushort*)d_ws;               // 163840 B scratch

    hipLaunchKernelGGL(prep_w, dim3(320), dim3(256), 0, stream, W, Wf);
    hipLaunchKernelGGL(gemm_ctc, dim3(B_ * T_ / ROWS_PB), dim3(640), 0, stream,
                       feat, Wf, bias, probs, lab);
}